// Round 1
// baseline (238.025 us; speedup 1.0000x reference)
//
#include <hip/hip_runtime.h>

#define Tn 1024
#define Hn 16
#define Dn 1024
#define DHn 64
// SCALE * log2(e): Q is pre-scaled by this, softmax then uses exp2 directly.
#define QSCALE 0.18033688011112042f

typedef unsigned short u16;
typedef __bf16 bf16x8 __attribute__((ext_vector_type(8)));
typedef float f32x4 __attribute__((ext_vector_type(4)));

__device__ __forceinline__ u16 f2bf(float f) {
  union { float f; unsigned u; } v; v.f = f;
  return (u16)((v.u + 0x7FFFu + ((v.u >> 16) & 1u)) >> 16);
}
__device__ __forceinline__ float bf2f(u16 s) {
  union { unsigned u; float f; } v; v.u = ((unsigned)s) << 16;
  return v.f;
}
__device__ __forceinline__ f32x4 mfma16(bf16x8 a, bf16x8 b, f32x4 c) {
  return __builtin_amdgcn_mfma_f32_16x16x32_bf16(a, b, c, 0, 0, 0);
}

// ---------------- convert fp32 -> bf16 (linear) ----------------
__global__ void k_convert(const float* __restrict__ src, u16* __restrict__ dst, int n) {
  int i = (blockIdx.x * blockDim.x + threadIdx.x) * 4;
  if (i >= n) return;
  float4 v = *(const float4*)(src + i);
  union { u16 s[4]; uint2 u; } o;
  o.s[0] = f2bf(v.x); o.s[1] = f2bf(v.y); o.s[2] = f2bf(v.z); o.s[3] = f2bf(v.w);
  *(uint2*)(dst + i) = o.u;
}

// ---------------- pack bool mask bytes -> 64-bit words (bit k = mask[base+k]) ----------------
__global__ __launch_bounds__(256) void k_maskpack(const unsigned char* __restrict__ m,
                                                  unsigned long long* __restrict__ mb) {
  int wi = blockIdx.x * 4 + (threadIdx.x >> 6);
  int lane = threadIdx.x & 63;
  unsigned char v = m[((size_t)wi << 6) + lane];
  unsigned long long bal = __ballot(v != 0);
  if (lane == 0) mb[wi] = bal;
}

// ---------------- transpose + convert: W[K][N] fp32 -> Wt[N][K] bf16 ----------------
__global__ void k_transpose_convert(const float* __restrict__ W, u16* __restrict__ Wt) {
  __shared__ float tile[32][33];
  int n0 = blockIdx.x * 32, k0 = blockIdx.y * 32;
  int tx = threadIdx.x, ty = threadIdx.y; // (32,8)
  #pragma unroll
  for (int i = 0; i < 4; i++)
    tile[ty + 8*i][tx] = W[(size_t)(k0 + ty + 8*i) * Dn + n0 + tx];
  __syncthreads();
  #pragma unroll
  for (int i = 0; i < 4; i++)
    Wt[(size_t)(n0 + ty + 8*i) * Dn + k0 + tx] = f2bf(tile[tx][ty + 8*i]);
}

// ---------------- GEMM: C[M,N] = A[M,K] @ B, given Bt[N,K]; bf16 in/out ----------------
// mode 0: scatter-write to [B,H,T,DH] with scale; cols 0..1023 -> dst0, 1024..2047 -> dst1.
// mode 1: linear write + fp32 bias.
__global__ __launch_bounds__(256) void k_gemm_bt(const u16* __restrict__ A, const u16* __restrict__ Bt,
                                                 u16* __restrict__ dst0, u16* __restrict__ dst1,
                                                 const float* __restrict__ bias, float scale, int mode) {
  __shared__ __align__(16) u16 Al[128][40];
  __shared__ __align__(16) u16 Bl[128][40];
  int m0 = blockIdx.y * 128, n0 = blockIdx.x * 128;
  int tid = threadIdx.x;
  int w = tid >> 6, lane = tid & 63, g = lane >> 4, lr = lane & 15;
  int wr = w >> 1, wc = w & 1;
  f32x4 acc[4][4] = {};
  int sr = tid >> 2, sc = tid & 3;
  const u16* Ap0 = &A[(size_t)(m0 + sr) * Dn + sc * 8];
  const u16* Ap1 = &A[(size_t)(m0 + sr + 64) * Dn + sc * 8];
  const u16* Bp0 = &Bt[(size_t)(n0 + sr) * Dn + sc * 8];
  const u16* Bp1 = &Bt[(size_t)(n0 + sr + 64) * Dn + sc * 8];
  int4 ra0 = *(const int4*)Ap0;
  int4 ra1 = *(const int4*)Ap1;
  int4 rb0 = *(const int4*)Bp0;
  int4 rb1 = *(const int4*)Bp1;
  for (int k0 = 0; k0 < Dn; k0 += 32) {
    __syncthreads();
    *(int4*)&Al[sr][sc*8]      = ra0;
    *(int4*)&Al[sr + 64][sc*8] = ra1;
    *(int4*)&Bl[sr][sc*8]      = rb0;
    *(int4*)&Bl[sr + 64][sc*8] = rb1;
    __syncthreads();
    if (k0 + 32 < Dn) {
      ra0 = *(const int4*)(Ap0 + k0 + 32);
      ra1 = *(const int4*)(Ap1 + k0 + 32);
      rb0 = *(const int4*)(Bp0 + k0 + 32);
      rb1 = *(const int4*)(Bp1 + k0 + 32);
    }
    bf16x8 a[4], b[4];
    #pragma unroll
    for (int mi = 0; mi < 4; mi++) a[mi] = *(const bf16x8*)&Al[wr*64 + mi*16 + lr][g*8];
    #pragma unroll
    for (int ni = 0; ni < 4; ni++) b[ni] = *(const bf16x8*)&Bl[wc*64 + ni*16 + lr][g*8];
    #pragma unroll
    for (int mi = 0; mi < 4; mi++)
      #pragma unroll
      for (int ni = 0; ni < 4; ni++)
        acc[mi][ni] = mfma16(a[mi], b[ni], acc[mi][ni]);
  }
  #pragma unroll
  for (int mi = 0; mi < 4; mi++)
    #pragma unroll
    for (int ni = 0; ni < 4; ni++)
      #pragma unroll
      for (int r = 0; r < 4; r++) {
        int row = m0 + wr*64 + mi*16 + g*4 + r;
        int col = n0 + wc*64 + ni*16 + lr;
        float v = acc[mi][ni][r];
        if (mode == 0) {
          int bb = row >> 10, tt = row & 1023, hh = col >> 6, dd = col & 63;
          u16* base = (hh < 16) ? dst0 : dst1;
          int hh2 = hh & 15;
          base[(((size_t)(bb*16 + hh2) << 10) + (size_t)tt) * 64 + dd] = f2bf(v * scale);
        } else {
          dst0[(size_t)row * Dn + col] = f2bf(v + bias[col]);
        }
      }
}

// ---------------- flash attention with Music-Transformer skew ----------------
// grid (T/64, H, B), block 256. Wave w owns q-rows q0+16w..+15.
__global__ __launch_bounds__(256) void k_attn(const u16* __restrict__ Qb, const u16* __restrict__ Kb,
                                              const u16* __restrict__ Vb, const u16* __restrict__ Eb,
                                              const unsigned long long* __restrict__ mbits,
                                              u16* __restrict__ ctx) {
  __shared__ __align__(16) u16 Kl[64][72];
  __shared__ __align__(16) u16 Vt[64][72];   // column-XOR-swizzled: V[kv][d] at Vt[d][kv ^ ((d>>3&7)<<3)]
  __shared__ __align__(16) u16 RP[4][16][72]; // per-wave P tile (bf16), 64 wide + pad
  int h = blockIdx.y, b = blockIdx.z;
  int q0 = blockIdx.x * 64;
  int tid = threadIdx.x;
  int w = tid >> 6, lane = tid & 63, g = lane >> 4, lr = lane & 15;
  int qw0 = q0 + w * 16;
  size_t headoff = (size_t)(b * Hn + h) * Tn * DHn;
  bf16x8 qf0 = *(const bf16x8*)&Qb[headoff + (size_t)(qw0 + lr)*64 + g*8];
  bf16x8 qf1 = *(const bf16x8*)&Qb[headoff + (size_t)(qw0 + lr)*64 + 32 + g*8];
  float mrun[4], lrun[4];
  f32x4 O[4] = {};
  #pragma unroll
  for (int r = 0; r < 4; r++) { mrun[r] = -INFINITY; lrun[r] = 0.f; }

  // loop-invariant skew-shuffle source lanes + register-set predicates:
  // skew(rowq,col) = REL[rowq][col-rowq+15]; producer lane = same g-group,
  // lane (lr-rowq+15)&15, register-set c (if lr<=rowq) else c+1, same reg r.
  int srcl[4]; bool psel[4];
  #pragma unroll
  for (int r = 0; r < 4; r++) {
    int rowq = g*4 + r;
    srcl[r] = (lane & 48) + ((lr - rowq + 15) & 15);
    psel[r] = (lr <= rowq);
  }
  // packed-mask row base: rows qw0+g*4+r, 16 words per row
  const unsigned long long* mrow = mbits + ((size_t)(b * Tn + qw0 + g*4) << 4);

  // staging: thread handles K/V rows (tid>>3) and (tid>>3)+32, col chunk (tid&7)*8
  int srow = tid >> 3, sc8 = tid & 7;
  const u16* Kg = Kb + headoff + (size_t)srow * 64 + sc8 * 8;
  const u16* Vg = Vb + headoff + (size_t)srow * 64 + sc8 * 8;
  int4 kA = *(const int4*)Kg;
  int4 kB = *(const int4*)(Kg + 32*64);
  int4 vA = *(const int4*)Vg;
  int4 vB = *(const int4*)(Vg + 32*64);
  int sw0 = srow ^ (sc8 << 3);
  int sw1 = (srow + 32) ^ (sc8 << 3);

  for (int k0 = 0; k0 < Tn; k0 += 64) {
    __syncthreads();
    *(int4*)&Kl[srow][sc8*8]      = kA;
    *(int4*)&Kl[srow + 32][sc8*8] = kB;
    {
      union { int4 v; u16 s[8]; } ua, ub;
      ua.v = vA; ub.v = vB;
      #pragma unroll
      for (int j = 0; j < 8; j++) {
        Vt[sc8*8 + j][sw0] = ua.s[j];
        Vt[sc8*8 + j][sw1] = ub.s[j];
      }
    }
    __syncthreads();
    if (k0 + 64 < Tn) {   // T14: prefetch next tile under this tile's compute
      kA = *(const int4*)(Kg + (size_t)(k0 + 64) * 64);
      kB = *(const int4*)(Kg + (size_t)(k0 + 96) * 64);
      vA = *(const int4*)(Vg + (size_t)(k0 + 64) * 64);
      vB = *(const int4*)(Vg + (size_t)(k0 + 96) * 64);
    }
    // packed mask words for this tile: bit (c*16+lr) of mw[r] masks (rowq, k0+c*16+lr)
    uint2 mw[4];
    #pragma unroll
    for (int r = 0; r < 4; r++)
      mw[r] = *(const uint2*)(mrow + (size_t)r * 16 + (k0 >> 6));

    // REL2[q][j] = Q[q] . E[rmin + j], j in [0,80) -- kept in registers
    int rmin = k0 - qw0 - 15 + (Tn - 1);
    f32x4 Rm[5];
    #pragma unroll
    for (int jt = 0; jt < 5; jt++) {
      f32x4 R = {0.f, 0.f, 0.f, 0.f};
      const u16* ep = &Eb[(size_t)(rmin + jt*16 + lr) * 64 + g*8];
      R = mfma16(qf0, *(const bf16x8*)ep, R);
      R = mfma16(qf1, *(const bf16x8*)(ep + 32), R);
      Rm[jt] = R;
    }
    // redistribute skew values in-register (ds_bpermute), Rm dies here
    float sh[5][4];
    #pragma unroll
    for (int s5 = 0; s5 < 5; s5++)
      #pragma unroll
      for (int r = 0; r < 4; r++)
        sh[s5][r] = __shfl(Rm[s5][r], srcl[r], 64);

    // S = Q K^T  (rows q, cols kv)
    f32x4 S[4];
    #pragma unroll
    for (int c = 0; c < 4; c++) {
      f32x4 z = {0.f, 0.f, 0.f, 0.f};
      bf16x8 kf0 = *(const bf16x8*)&Kl[c*16 + lr][g*8];
      bf16x8 kf1 = *(const bf16x8*)&Kl[c*16 + lr][32 + g*8];
      z = mfma16(qf0, kf0, z);
      z = mfma16(qf1, kf1, z);
      S[c] = z;
    }

    // combine + mask (scores already carry SCALE*log2e via Q pre-scale)
    float p[4][4];
    float tmax[4];
    #pragma unroll
    for (int r = 0; r < 4; r++) tmax[r] = -INFINITY;
    #pragma unroll
    for (int c = 0; c < 4; c++)
      #pragma unroll
      for (int r = 0; r < 4; r++) {
        float s = S[c][r] + (psel[r] ? sh[c][r] : sh[c+1][r]);
        unsigned bit;
        if (c == 0)      bit = (mw[r].x >> lr) & 1u;
        else if (c == 1) bit = (mw[r].x >> (16 + lr)) & 1u;
        else if (c == 2) bit = (mw[r].y >> lr) & 1u;
        else             bit = (mw[r].y >> (16 + lr)) & 1u;
        s = bit ? -1e9f : s;
        p[c][r] = s;
        tmax[r] = fmaxf(tmax[r], s);
      }
    #pragma unroll
    for (int r = 0; r < 4; r++)
      #pragma unroll
      for (int off = 1; off < 16; off <<= 1)
        tmax[r] = fmaxf(tmax[r], __shfl_xor(tmax[r], off));
    float alpha[4];
    #pragma unroll
    for (int r = 0; r < 4; r++) {
      float mn = fmaxf(mrun[r], tmax[r]);
      alpha[r] = __builtin_amdgcn_exp2f(mrun[r] - mn);
      mrun[r] = mn;
    }
    float rs[4];
    #pragma unroll
    for (int r = 0; r < 4; r++) rs[r] = 0.f;
    #pragma unroll
    for (int c = 0; c < 4; c++)
      #pragma unroll
      for (int r = 0; r < 4; r++) {
        float pv = __builtin_amdgcn_exp2f(p[c][r] - mrun[r]);
        p[c][r] = pv;
        rs[r] += pv;
      }
    #pragma unroll
    for (int r = 0; r < 4; r++) {
      #pragma unroll
      for (int off = 1; off < 16; off <<= 1)
        rs[r] += __shfl_xor(rs[r], off);
      lrun[r] = lrun[r] * alpha[r] + rs[r];
    }
    // write P (bf16) into the per-wave buffer
    #pragma unroll
    for (int c = 0; c < 4; c++)
      #pragma unroll
      for (int r = 0; r < 4; r++)
        RP[w][g*4 + r][c*16 + lr] = f2bf(p[c][r]);
    // rescale O
    #pragma unroll
    for (int ct = 0; ct < 4; ct++)
      #pragma unroll
      for (int r = 0; r < 4; r++)
        O[ct][r] *= alpha[r];
    // PV
    bf16x8 pa0 = *(const bf16x8*)&RP[w][lr][g*8];
    bf16x8 pa1 = *(const bf16x8*)&RP[w][lr][32 + g*8];
    #pragma unroll
    for (int ct = 0; ct < 4; ct++) {
      int key = (ct*2 + (lr >> 3)) & 7;
      bf16x8 vf0 = *(const bf16x8*)&Vt[ct*16 + lr][(g ^ key) * 8];
      bf16x8 vf1 = *(const bf16x8*)&Vt[ct*16 + lr][((g + 4) ^ key) * 8];
      O[ct] = mfma16(pa0, vf0, O[ct]);
      O[ct] = mfma16(pa1, vf1, O[ct]);
    }
  }
  float inv[4];
  #pragma unroll
  for (int r = 0; r < 4; r++) inv[r] = 1.f / lrun[r];
  #pragma unroll
  for (int ct = 0; ct < 4; ct++)
    #pragma unroll
    for (int r = 0; r < 4; r++) {
      int rowq = g*4 + r, col = ct*16 + lr;
      ctx[(size_t)(b*Tn + qw0 + rowq) * 1024 + h*64 + col] = f2bf(O[ct][r] * inv[r]);
    }
}

// ---------------- residual + LayerNorm ----------------
__global__ __launch_bounds__(256) void k_ln(const float* __restrict__ x, const u16* __restrict__ o,
                                            const float* __restrict__ gamma, const float* __restrict__ beta,
                                            float* __restrict__ out) {
  int m = blockIdx.x, tid = threadIdx.x;
  int w = tid >> 6, lane = tid & 63;
  const float* xr = x + (size_t)m * Dn;
  const u16* orow = o + (size_t)m * Dn;
  float4 xv = *(const float4*)&xr[tid*4];
  union { uint2 u; u16 s[4]; } ou;
  ou.u = *(const uint2*)&orow[tid*4];
  float y[4];
  y[0] = xv.x + bf2f(ou.s[0]);
  y[1] = xv.y + bf2f(ou.s[1]);
  y[2] = xv.z + bf2f(ou.s[2]);
  y[3] = xv.w + bf2f(ou.s[3]);
  float s = y[0]+y[1]+y[2]+y[3];
  float s2 = y[0]*y[0]+y[1]*y[1]+y[2]*y[2]+y[3]*y[3];
  #pragma unroll
  for (int off = 1; off < 64; off <<= 1) { s += __shfl_xor(s, off); s2 += __shfl_xor(s2, off); }
  __shared__ float red[8];
  if (lane == 0) { red[w] = s; red[4 + w] = s2; }
  __syncthreads();
  float Sa = red[0]+red[1]+red[2]+red[3];
  float Sb = red[4]+red[5]+red[6]+red[7];
  float mu = Sa * (1.f/1024.f);
  float var = Sb * (1.f/1024.f) - mu*mu;
  float rstd = rsqrtf(var + 1e-5f);
  #pragma unroll
  for (int i = 0; i < 4; i++) {
    int j = tid*4 + i;
    out[(size_t)m*Dn + j] = (y[i] - mu) * rstd * gamma[j] + beta[j];
  }
}

extern "C" void kernel_launch(void* const* d_in, const int* in_sizes, int n_in,
                              void* d_out, int out_size, void* d_ws, size_t ws_size,
                              hipStream_t stream) {
  const float* x    = (const float*)d_in[0];
  const float* ctxI = (const float*)d_in[1];
  const unsigned char* mask = (const unsigned char*)d_in[2];
  const float* lut  = (const float*)d_in[3];
  const float* Wq   = (const float*)d_in[4];
  const float* Wk   = (const float*)d_in[5];
  const float* Wv   = (const float*)d_in[6];
  const float* Wo   = (const float*)d_in[7];
  const float* bo   = (const float*)d_in[8];
  const float* gamma= (const float*)d_in[9];
  const float* beta = (const float*)d_in[10];
  float* out = (float*)d_out;

  u16* xbf = (u16*)d_ws;
  u16* cbf  = xbf + 4194304;
  u16* WqT  = cbf + 4194304;
  u16* WkT  = WqT + 1048576;
  u16* WvT  = WkT + 1048576;   // contiguous with WkT -> fused KV GEMM reads [2048][1024]
  u16* WoT  = WvT + 1048576;
  u16* Ebf  = WoT + 1048576;
  u16* Qbf  = Ebf + 131072;
  u16* Kbf  = Qbf + 4194304;
  u16* Vbf  = Kbf + 4194304;
  u16* ctxb = Vbf + 4194304;
  u16* obf  = ctxb + 4194304;
  unsigned long long* mbits = (unsigned long long*)(obf + 4194304); // 65536 words = 512 KB

  k_maskpack<<<16384, 256, 0, stream>>>(mask, mbits);
  k_convert<<<4096, 256, 0, stream>>>(x, xbf, 4194304);
  k_convert<<<4096, 256, 0, stream>>>(ctxI, cbf, 4194304);
  k_convert<<<128, 256, 0, stream>>>(lut, Ebf, 131008);
  dim3 tb(32, 8), tg(32, 32);
  k_transpose_convert<<<tg, tb, 0, stream>>>(Wq, WqT);
  k_transpose_convert<<<tg, tb, 0, stream>>>(Wk, WkT);
  k_transpose_convert<<<tg, tb, 0, stream>>>(Wv, WvT);
  k_transpose_convert<<<tg, tb, 0, stream>>>(Wo, WoT);
  k_gemm_bt<<<dim3(8, 32),  256, 0, stream>>>(xbf, WqT, Qbf, nullptr, nullptr, QSCALE, 0);
  k_gemm_bt<<<dim3(16, 32), 256, 0, stream>>>(cbf, WkT, Kbf, Vbf,    nullptr, 1.0f,   0);
  k_attn<<<dim3(16, 16, 4), 256, 0, stream>>>(Qbf, Kbf, Vbf, Ebf, mbits, ctxb);
  k_gemm_bt<<<dim3(8, 32),  256, 0, stream>>>(ctxb, WoT, obf, nullptr, bo, 1.0f, 1);
  k_ln<<<4096, 256, 0, stream>>>(x, obf, gamma, beta, out);
}